// Round 1
// baseline (4576.640 us; speedup 1.0000x reference)
//
#include <hip/hip_runtime.h>
#include <math.h>

// Swin block forward: B=2, IMG=128, E=256, NH=8, HD=32, WS=8, T=64, L=4, HID=1024
#define E_DIM 256
#define NPB 16384           // tokens per batch = 128*128
#define M_TOT 32768         // total tokens

// ---------------- input embed: seq[b,n,e] = x[b,:,n]·in_w[e,:] + in_b[e] + pos[e,n]
__global__ __launch_bounds__(256) void embed_kernel(
    const float* __restrict__ x, const float* __restrict__ in_w,
    const float* __restrict__ in_b, const float* __restrict__ pos,
    float* __restrict__ seq)
{
  int idx = blockIdx.x * 256 + threadIdx.x;     // 2*16384*256 = 2^23 total
  int e = idx & 255;
  int n = (idx >> 8) & (NPB - 1);
  int b = idx >> 22;
  float x0 = x[b*3*NPB + 0*NPB + n];
  float x1 = x[b*3*NPB + 1*NPB + n];
  float x2 = x[b*3*NPB + 2*NPB + n];
  float v = x0*in_w[e*3+0] + x1*in_w[e*3+1] + x2*in_w[e*3+2]
          + in_b[e] + pos[(size_t)e*NPB + n];
  seq[((size_t)(b*NPB + n))*E_DIM + e] = v;
}

// ---------------- layernorm over E=256, one wave per token, 4 tokens per block
__global__ __launch_bounds__(256) void ln_kernel(
    const float* __restrict__ x, const float* __restrict__ g,
    const float* __restrict__ b, float* __restrict__ y)
{
  int token = blockIdx.x * 4 + (threadIdx.x >> 6);
  int lane  = threadIdx.x & 63;
  const float4* xr = (const float4*)(x + (size_t)token * E_DIM);
  float4 v = xr[lane];
  float s = v.x + v.y + v.z + v.w;
  #pragma unroll
  for (int off = 32; off; off >>= 1) s += __shfl_xor(s, off);
  float mean = s * (1.0f / E_DIM);
  float d0 = v.x - mean, d1 = v.y - mean, d2 = v.z - mean, d3 = v.w - mean;
  float q = d0*d0 + d1*d1 + d2*d2 + d3*d3;
  #pragma unroll
  for (int off = 32; off; off >>= 1) q += __shfl_xor(q, off);
  float rstd = rsqrtf(q * (1.0f / E_DIM) + 1e-5f);
  float4 gg = ((const float4*)g)[lane];
  float4 bb = ((const float4*)b)[lane];
  float4 o;
  o.x = d0 * rstd * gg.x + bb.x;
  o.y = d1 * rstd * gg.y + bb.y;
  o.z = d2 * rstd * gg.z + bb.z;
  o.w = d3 * rstd * gg.w + bb.w;
  ((float4*)(y + (size_t)token * E_DIM))[lane] = o;
}

// ---------------- generic fp32 GEMM: C[M,N] = A[M,K] @ W + bias (+gelu)(+res)
// WT: W stored [N,K] (use for out_w). OCHW: write channel-major [b,e,n].
template<int ACT, int RES, int WT, int OCHW>
__global__ __launch_bounds__(256) void gemm_kernel(
    const float* __restrict__ A, const float* __restrict__ W,
    const float* __restrict__ bias, const float* __restrict__ Res,
    float* __restrict__ C, int M, int N, int K)
{
  __shared__ float As[16][65];
  __shared__ float Ws[16][65];
  int bn = blockIdx.x * 64;
  int bm = blockIdx.y * 64;
  int tid = threadIdx.x;
  int tx = tid & 15, ty = tid >> 4;
  float acc[4][4] = {};
  for (int k0 = 0; k0 < K; k0 += 16) {
    {
      int m = tid >> 2, k4 = (tid & 3) * 4;
      float4 a = *(const float4*)(A + (size_t)(bm + m) * K + k0 + k4);
      As[k4+0][m] = a.x; As[k4+1][m] = a.y; As[k4+2][m] = a.z; As[k4+3][m] = a.w;
    }
    if (WT) {
      int n = tid >> 2, k4 = (tid & 3) * 4;
      float4 w = *(const float4*)(W + (size_t)(bn + n) * K + k0 + k4);
      Ws[k4+0][n] = w.x; Ws[k4+1][n] = w.y; Ws[k4+2][n] = w.z; Ws[k4+3][n] = w.w;
    } else {
      int k = tid >> 4, n4 = (tid & 15) * 4;
      float4 w = *(const float4*)(W + (size_t)(k0 + k) * N + bn + n4);
      Ws[k][n4+0] = w.x; Ws[k][n4+1] = w.y; Ws[k][n4+2] = w.z; Ws[k][n4+3] = w.w;
    }
    __syncthreads();
    #pragma unroll
    for (int k = 0; k < 16; k++) {
      float a[4], w[4];
      #pragma unroll
      for (int i = 0; i < 4; i++) a[i] = As[k][ty*4 + i];
      #pragma unroll
      for (int j = 0; j < 4; j++) w[j] = Ws[k][tx*4 + j];
      #pragma unroll
      for (int i = 0; i < 4; i++)
        #pragma unroll
        for (int j = 0; j < 4; j++)
          acc[i][j] += a[i] * w[j];
    }
    __syncthreads();
  }
  #pragma unroll
  for (int i = 0; i < 4; i++) {
    int row = bm + ty*4 + i;
    #pragma unroll
    for (int j = 0; j < 4; j++) {
      int col = bn + tx*4 + j;
      float v = acc[i][j] + bias[col];
      if (ACT) v = 0.5f * v * (1.0f + erff(v * 0.70710678118654752f));  // exact gelu
      if (RES) v += Res[(size_t)row * N + col];
      if (OCHW) {
        int b = row >> 14, n = row & (NPB - 1);
        C[(size_t)b * E_DIM * NPB + (size_t)col * NPB + n] = v;
      } else {
        C[(size_t)row * N + col] = v;
      }
    }
  }
}

// ---------------- window attention: one wave per (window, head)
// qkv: [M_TOT, 768] in token order; gather/scatter applies the shift roll.
// Swin mask computed analytically: regions split at h,w in {120,124}.
__global__ __launch_bounds__(64) void attn_kernel(
    const float* __restrict__ qkv, float* __restrict__ out, int shifted)
{
  __shared__ float Ks[64 * 32];
  __shared__ float Vs[64 * 32];
  int wid  = blockIdx.x;          // 0..511 (b*256 + window)
  int head = blockIdx.y;          // 0..7
  int b = wid >> 8;
  int w = wid & 255;
  int wh = w >> 4, ww = w & 15;
  int t = threadIdx.x;            // query token within window
  int r = t >> 3, c = t & 7;
  int hs  = wh * 8 + r;           // coords in (possibly shifted) frame
  int wsn = ww * 8 + c;
  int h0 = shifted ? ((hs  + 4) & 127) : hs;
  int w0 = shifted ? ((wsn + 4) & 127) : wsn;
  int tok = b * NPB + h0 * 128 + w0;
  const float* base = qkv + (size_t)tok * 768 + head * 32;
  float4 q[8];
  #pragma unroll
  for (int d4 = 0; d4 < 8; d4++) {
    q[d4] = *(const float4*)(base + d4 * 4);
    *(float4*)(Ks + t*32 + d4*4) = *(const float4*)(base + 256 + d4*4);
    *(float4*)(Vs + t*32 + d4*4) = *(const float4*)(base + 512 + d4*4);
  }
  __syncthreads();
  int myreg = 0;
  if (shifted) {
    int sh = (hs  < 120) ? 0 : ((hs  < 124) ? 1 : 2);
    int sw = (wsn < 120) ? 0 : ((wsn < 124) ? 1 : 2);
    myreg = sh * 3 + sw;
  }
  const float scale = 0.17677669529663687f;   // 32^-0.5
  // pass 1: row max
  float mmax = -1e30f;
  for (int s = 0; s < 64; s++) {
    float dot = 0.f;
    #pragma unroll
    for (int d4 = 0; d4 < 8; d4++) {
      float4 kk = *(const float4*)(Ks + s*32 + d4*4);
      dot += q[d4].x*kk.x + q[d4].y*kk.y + q[d4].z*kk.z + q[d4].w*kk.w;
    }
    dot *= scale;
    if (shifted) {
      int hs2 = wh*8 + (s >> 3), ws2 = ww*8 + (s & 7);
      int reg2 = ((hs2 < 120) ? 0 : ((hs2 < 124) ? 1 : 2)) * 3
               + ((ws2 < 120) ? 0 : ((ws2 < 124) ? 1 : 2));
      if (reg2 != myreg) dot -= 100.0f;
    }
    mmax = fmaxf(mmax, dot);
  }
  // pass 2: exp-sum and PV accumulate (recompute scores; attention is tiny)
  float l = 0.f;
  float acc[32] = {};
  for (int s = 0; s < 64; s++) {
    float dot = 0.f;
    #pragma unroll
    for (int d4 = 0; d4 < 8; d4++) {
      float4 kk = *(const float4*)(Ks + s*32 + d4*4);
      dot += q[d4].x*kk.x + q[d4].y*kk.y + q[d4].z*kk.z + q[d4].w*kk.w;
    }
    dot *= scale;
    if (shifted) {
      int hs2 = wh*8 + (s >> 3), ws2 = ww*8 + (s & 7);
      int reg2 = ((hs2 < 120) ? 0 : ((hs2 < 124) ? 1 : 2)) * 3
               + ((ws2 < 120) ? 0 : ((ws2 < 124) ? 1 : 2));
      if (reg2 != myreg) dot -= 100.0f;
    }
    float p = __expf(dot - mmax);
    l += p;
    #pragma unroll
    for (int d = 0; d < 32; d++) acc[d] += p * Vs[s*32 + d];
  }
  float inv = 1.0f / l;
  float* ob = out + (size_t)tok * E_DIM + head * 32;
  #pragma unroll
  for (int d = 0; d < 32; d++) ob[d] = acc[d] * inv;
}

extern "C" void kernel_launch(void* const* d_in, const int* in_sizes, int n_in,
                              void* d_out, int out_size, void* d_ws, size_t ws_size,
                              hipStream_t stream) {
  (void)in_sizes; (void)n_in; (void)out_size; (void)ws_size;
  const float* x      = (const float*)d_in[0];
  const float* in_w   = (const float*)d_in[1];
  const float* in_b   = (const float*)d_in[2];
  const float* pos    = (const float*)d_in[3];
  const float* ln1_g  = (const float*)d_in[4];
  const float* ln1_b  = (const float*)d_in[5];
  const float* qkv_w  = (const float*)d_in[6];
  const float* qkv_b  = (const float*)d_in[7];
  const float* proj_w = (const float*)d_in[8];
  const float* proj_b = (const float*)d_in[9];
  const float* ln2_g  = (const float*)d_in[10];
  const float* ln2_b  = (const float*)d_in[11];
  const float* mlp_w1 = (const float*)d_in[12];
  const float* mlp_b1 = (const float*)d_in[13];
  const float* mlp_w2 = (const float*)d_in[14];
  const float* mlp_b2 = (const float*)d_in[15];
  const float* out_w  = (const float*)d_in[16];
  const float* out_b  = (const float*)d_in[17];
  float* outp = (float*)d_out;

  // workspace: seq | h (LN out, reused as attn-out) | big (qkv / mlp hidden)
  float* seq = (float*)d_ws;                       // 32768*256
  float* h   = seq + (size_t)M_TOT * E_DIM;        // 32768*256
  float* big = h   + (size_t)M_TOT * E_DIM;        // 32768*1024

  embed_kernel<<<32768, 256, 0, stream>>>(x, in_w, in_b, pos, seq);

  for (int i = 0; i < 4; i++) {
    int shifted = i & 1;
    // LN1
    ln_kernel<<<8192, 256, 0, stream>>>(seq, ln1_g + i*256, ln1_b + i*256, h);
    // QKV: [32768,256] @ [256,768] -> big
    gemm_kernel<0,0,0,0><<<dim3(12, 512), 256, 0, stream>>>(
        h, qkv_w + (size_t)i*256*768, qkv_b + i*768, nullptr, big, M_TOT, 768, 256);
    // attention (writes merged, pre-proj output into h)
    attn_kernel<<<dim3(512, 8), 64, 0, stream>>>(big, h, shifted);
    // proj + residual: seq += h @ proj_w + proj_b
    gemm_kernel<0,1,0,0><<<dim3(4, 512), 256, 0, stream>>>(
        h, proj_w + (size_t)i*256*256, proj_b + i*256, seq, seq, M_TOT, 256, 256);
    // LN2
    ln_kernel<<<8192, 256, 0, stream>>>(seq, ln2_g + i*256, ln2_b + i*256, h);
    // MLP1 + gelu: [32768,256] @ [256,1024] -> big
    gemm_kernel<1,0,0,0><<<dim3(16, 512), 256, 0, stream>>>(
        h, mlp_w1 + (size_t)i*256*1024, mlp_b1 + i*1024, nullptr, big, M_TOT, 1024, 256);
    // MLP2 + residual: seq += big @ mlp_w2 + mlp_b2
    gemm_kernel<0,1,0,0><<<dim3(4, 512), 256, 0, stream>>>(
        big, mlp_w2 + (size_t)i*1024*256, mlp_b2 + i*256, seq, seq, M_TOT, 256, 1024);
  }

  // final: out[b,e,n] = seq[b,n,:] · out_w[e,:] + out_b[e]  (WT + channel-major store)
  gemm_kernel<0,0,1,1><<<dim3(4, 512), 256, 0, stream>>>(
      seq, out_w, out_b, nullptr, outp, M_TOT, 256, 256);
}

// Round 3
// 1215.471 us; speedup vs baseline: 3.7653x; 3.7653x over previous
//
#include <hip/hip_runtime.h>
#include <math.h>

// Swin block forward: B=2, IMG=128, E=256, NH=8, HD=32, WS=8, T=64, L=4, HID=1024
#define E_DIM 256
#define NPB 16384           // tokens per batch = 128*128
#define M_TOT 32768         // total tokens

typedef __attribute__((ext_vector_type(4))) float f32x4;
typedef __attribute__((ext_vector_type(8))) short s16x8;

__device__ inline unsigned short f2bu(float f) {       // fp32 -> bf16 bits (RNE)
  union { float f; unsigned int i; } x; x.f = f;
  unsigned int r = x.i + 0x7fffu + ((x.i >> 16) & 1u);
  return (unsigned short)(r >> 16);
}
__device__ inline float bu2f(unsigned short u) {
  union { unsigned int i; float f; } x; x.i = ((unsigned int)u) << 16; return x.f;
}
__device__ inline void gload16(const void* g, void* l) {
  __builtin_amdgcn_global_load_lds(
      (const __attribute__((address_space(1))) void*)g,
      (__attribute__((address_space(3))) void*)l, 16, 0, 0);
}

// ---------------- input embed (unchanged, fp32 out)
__global__ __launch_bounds__(256) void embed_kernel(
    const float* __restrict__ x, const float* __restrict__ in_w,
    const float* __restrict__ in_b, const float* __restrict__ pos,
    float* __restrict__ seq)
{
  int idx = blockIdx.x * 256 + threadIdx.x;
  int e = idx & 255;
  int n = (idx >> 8) & (NPB - 1);
  int b = idx >> 22;
  float x0 = x[b*3*NPB + 0*NPB + n];
  float x1 = x[b*3*NPB + 1*NPB + n];
  float x2 = x[b*3*NPB + 2*NPB + n];
  float v = x0*in_w[e*3+0] + x1*in_w[e*3+1] + x2*in_w[e*3+2]
          + in_b[e] + pos[(size_t)e*NPB + n];
  seq[((size_t)(b*NPB + n))*E_DIM + e] = v;
}

// ---------------- layernorm fp32 in -> bf16 out, one wave per token
__global__ __launch_bounds__(256) void ln_kernel(
    const float* __restrict__ x, const float* __restrict__ g,
    const float* __restrict__ b, unsigned short* __restrict__ y)
{
  int token = blockIdx.x * 4 + (threadIdx.x >> 6);
  int lane  = threadIdx.x & 63;
  const float4* xr = (const float4*)(x + (size_t)token * E_DIM);
  float4 v = xr[lane];
  float s = v.x + v.y + v.z + v.w;
  #pragma unroll
  for (int off = 32; off; off >>= 1) s += __shfl_xor(s, off);
  float mean = s * (1.0f / E_DIM);
  float d0 = v.x - mean, d1 = v.y - mean, d2 = v.z - mean, d3 = v.w - mean;
  float q = d0*d0 + d1*d1 + d2*d2 + d3*d3;
  #pragma unroll
  for (int off = 32; off; off >>= 1) q += __shfl_xor(q, off);
  float rstd = rsqrtf(q * (1.0f / E_DIM) + 1e-5f);
  float4 gg = ((const float4*)g)[lane];
  float4 bb = ((const float4*)b)[lane];
  ushort4 o;
  o.x = f2bu(d0 * rstd * gg.x + bb.x);
  o.y = f2bu(d1 * rstd * gg.y + bb.y);
  o.z = f2bu(d2 * rstd * gg.z + bb.z);
  o.w = f2bu(d3 * rstd * gg.w + bb.w);
  *(ushort4*)(y + (size_t)token * E_DIM + lane * 4) = o;
}

// ---------------- weight transpose+convert: W[K,N] fp32 -> Wt[N,K] bf16
__global__ __launch_bounds__(256) void wconv_t(
    const float* __restrict__ W, unsigned short* __restrict__ Wt, int K, int N)
{
  __shared__ float t[32][33];
  int nb = blockIdx.x * 32, kb = blockIdx.y * 32;
  int tx = threadIdx.x & 31, ty = threadIdx.x >> 5;   // ty 0..7
  #pragma unroll
  for (int i = 0; i < 32; i += 8)
    t[ty + i][tx] = W[(size_t)(kb + ty + i) * N + nb + tx];
  __syncthreads();
  #pragma unroll
  for (int i = 0; i < 32; i += 8)
    Wt[(size_t)(nb + ty + i) * K + kb + tx] = f2bu(t[tx][ty + i]);
}

// ---------------- elementwise fp32 -> bf16 (n divisible by 1024)
__global__ __launch_bounds__(256) void bconv(
    const float* __restrict__ a, unsigned short* __restrict__ o, int n)
{
  int i = blockIdx.x * 1024 + threadIdx.x * 4;
  float4 v = *(const float4*)(a + i);
  ushort4 u; u.x = f2bu(v.x); u.y = f2bu(v.y); u.z = f2bu(v.z); u.w = f2bu(v.w);
  *(ushort4*)(o + i) = u;
}

// ---------------- bf16 MFMA GEMM, 128x128 tile, BK=32, 4 waves, m97 structure
// A[M,K] bf16, Wt[N,K] bf16 (B pre-transposed). C variants via template.
template<int ACT, int RES, int OCHW, int OBF>
__global__ __launch_bounds__(256) void mgemm(
    const unsigned short* __restrict__ A, const unsigned short* __restrict__ Wt,
    const float* __restrict__ bias, float* __restrict__ Res,
    void* __restrict__ Cv, int M, int N, int K)
{
  __shared__ unsigned short Al[128 * 32];
  __shared__ unsigned short Bl[128 * 32];
  const int tid  = threadIdx.x;
  const int lane = tid & 63;
  const int wid  = tid >> 6;
  const int wr = wid >> 1, wc = wid & 1;      // 2x2 waves, 64x64 each
  const int bn = blockIdx.x * 128, bm = blockIdx.y * 128;

  f32x4 acc[4][4];
  #pragma unroll
  for (int m = 0; m < 4; m++)
    #pragma unroll
    for (int n = 0; n < 4; n++)
      acc[m][n] = (f32x4){0.f, 0.f, 0.f, 0.f};

  const int srow = tid >> 2;            // 0..63
  const int scol = (tid & 3) * 8;       // bf16 element offset (16B chunk)
  const size_t arow = (size_t)(bm + srow);
  const size_t brow = (size_t)(bn + srow);
  char* aldst = (char*)Al + tid * 16;
  char* bldst = (char*)Bl + tid * 16;

  const char* abase = (const char*)Al + (wr*64 + (lane & 15)) * 64 + (lane >> 4) * 16;
  const char* bbase = (const char*)Bl + (wc*64 + (lane & 15)) * 64 + (lane >> 4) * 16;

  for (int k0 = 0; k0 < K; k0 += 32) {
    gload16(A  + arow       * K + k0 + scol, aldst);
    gload16(A  + (arow + 64)* K + k0 + scol, aldst + 4096);
    gload16(Wt + brow       * K + k0 + scol, bldst);
    gload16(Wt + (brow + 64)* K + k0 + scol, bldst + 4096);
    __syncthreads();
    s16x8 af[4], bf_[4];
    #pragma unroll
    for (int m = 0; m < 4; m++) af[m]  = *(const s16x8*)(abase + m * 1024);
    #pragma unroll
    for (int n = 0; n < 4; n++) bf_[n] = *(const s16x8*)(bbase + n * 1024);
    #pragma unroll
    for (int m = 0; m < 4; m++)
      #pragma unroll
      for (int n = 0; n < 4; n++)
        acc[m][n] = __builtin_amdgcn_mfma_f32_16x16x32_bf16(af[m], bf_[n], acc[m][n], 0, 0, 0);
    __syncthreads();
  }

  // epilogue: C/D map col = lane&15, row = (lane>>4)*4 + j
  float bv[4];
  #pragma unroll
  for (int n = 0; n < 4; n++) bv[n] = bias[bn + wc*64 + n*16 + (lane & 15)];

  #pragma unroll
  for (int m = 0; m < 4; m++) {
    int row0 = bm + wr*64 + m*16 + (lane >> 4) * 4;
    #pragma unroll
    for (int n = 0; n < 4; n++) {
      int col = bn + wc*64 + n*16 + (lane & 15);
      if (OCHW) {
        int bb = row0 >> 14, n0 = row0 & (NPB - 1);
        float4 st;
        st.x = acc[m][n][0] + bv[n]; st.y = acc[m][n][1] + bv[n];
        st.z = acc[m][n][2] + bv[n]; st.w = acc[m][n][3] + bv[n];
        *(float4*)((float*)Cv + (size_t)bb * E_DIM * NPB + (size_t)col * NPB + n0) = st;
      } else {
        #pragma unroll
        for (int j = 0; j < 4; j++) {
          int row = row0 + j;
          float v = acc[m][n][j] + bv[n];
          if (ACT) v = 0.5f * v * (1.0f + erff(v * 0.70710678118654752f));
          if (RES) { v += Res[(size_t)row * N + col]; Res[(size_t)row * N + col] = v; }
          else if (OBF) ((unsigned short*)Cv)[(size_t)row * N + col] = f2bu(v);
          else ((float*)Cv)[(size_t)row * N + col] = v;
        }
      }
    }
  }
}

// ---------------- window attention, bf16 in/out, fp32 compute
__global__ __launch_bounds__(64) void attn_kernel(
    const unsigned short* __restrict__ qkv, unsigned short* __restrict__ out, int shifted)
{
  __shared__ float Ks[64 * 32];
  __shared__ float Vs[64 * 32];
  int wid  = blockIdx.x;          // b*256 + window
  int head = blockIdx.y;
  int b = wid >> 8;
  int w = wid & 255;
  int wh = w >> 4, ww = w & 15;
  int t = threadIdx.x;
  int r = t >> 3, c = t & 7;
  int hs  = wh * 8 + r;
  int wsn = ww * 8 + c;
  int h0 = shifted ? ((hs  + 4) & 127) : hs;
  int w0 = shifted ? ((wsn + 4) & 127) : wsn;
  int tok = b * NPB + h0 * 128 + w0;
  const unsigned short* base = qkv + (size_t)tok * 768 + head * 32;
  float q[32];
  #pragma unroll
  for (int d8 = 0; d8 < 4; d8++) {
    s16x8 qv = *(const s16x8*)(base + d8 * 8);
    s16x8 kv = *(const s16x8*)(base + 256 + d8 * 8);
    s16x8 vv = *(const s16x8*)(base + 512 + d8 * 8);
    #pragma unroll
    for (int j = 0; j < 8; j++) {
      q[d8*8 + j] = bu2f((unsigned short)qv[j]);
      Ks[t*32 + d8*8 + j] = bu2f((unsigned short)kv[j]);
      Vs[t*32 + d8*8 + j] = bu2f((unsigned short)vv[j]);
    }
  }
  __syncthreads();
  int myreg = 0;
  if (shifted) {
    int sh = (hs  < 120) ? 0 : ((hs  < 124) ? 1 : 2);
    int sw = (wsn < 120) ? 0 : ((wsn < 124) ? 1 : 2);
    myreg = sh * 3 + sw;
  }
  const float scale = 0.17677669529663687f;
  float mmax = -1e30f;
  for (int s = 0; s < 64; s++) {
    float dot = 0.f;
    #pragma unroll
    for (int d4 = 0; d4 < 8; d4++) {
      float4 kk = *(const float4*)(Ks + s*32 + d4*4);
      dot += q[d4*4+0]*kk.x + q[d4*4+1]*kk.y + q[d4*4+2]*kk.z + q[d4*4+3]*kk.w;
    }
    dot *= scale;
    if (shifted) {
      int hs2 = wh*8 + (s >> 3), ws2 = ww*8 + (s & 7);
      int reg2 = ((hs2 < 120) ? 0 : ((hs2 < 124) ? 1 : 2)) * 3
               + ((ws2 < 120) ? 0 : ((ws2 < 124) ? 1 : 2));
      if (reg2 != myreg) dot -= 100.0f;
    }
    mmax = fmaxf(mmax, dot);
  }
  float l = 0.f;
  float acc[32] = {};
  for (int s = 0; s < 64; s++) {
    float dot = 0.f;
    #pragma unroll
    for (int d4 = 0; d4 < 8; d4++) {
      float4 kk = *(const float4*)(Ks + s*32 + d4*4);
      dot += q[d4*4+0]*kk.x + q[d4*4+1]*kk.y + q[d4*4+2]*kk.z + q[d4*4+3]*kk.w;
    }
    dot *= scale;
    if (shifted) {
      int hs2 = wh*8 + (s >> 3), ws2 = ww*8 + (s & 7);
      int reg2 = ((hs2 < 120) ? 0 : ((hs2 < 124) ? 1 : 2)) * 3
               + ((ws2 < 120) ? 0 : ((ws2 < 124) ? 1 : 2));
      if (reg2 != myreg) dot -= 100.0f;
    }
    float p = __expf(dot - mmax);
    l += p;
    #pragma unroll
    for (int d = 0; d < 32; d++) acc[d] += p * Vs[s*32 + d];
  }
  float inv = 1.0f / l;
  unsigned short* ob = out + (size_t)tok * E_DIM + head * 32;
  #pragma unroll
  for (int d8 = 0; d8 < 8; d8++) {
    ushort4 o;
    o.x = f2bu(acc[d8*4+0] * inv); o.y = f2bu(acc[d8*4+1] * inv);
    o.z = f2bu(acc[d8*4+2] * inv); o.w = f2bu(acc[d8*4+3] * inv);
    *(ushort4*)(ob + d8*4) = o;
  }
}

extern "C" void kernel_launch(void* const* d_in, const int* in_sizes, int n_in,
                              void* d_out, int out_size, void* d_ws, size_t ws_size,
                              hipStream_t stream) {
  (void)in_sizes; (void)n_in; (void)out_size; (void)ws_size;
  const float* x      = (const float*)d_in[0];
  const float* in_w   = (const float*)d_in[1];
  const float* in_b   = (const float*)d_in[2];
  const float* pos    = (const float*)d_in[3];
  const float* ln1_g  = (const float*)d_in[4];
  const float* ln1_b  = (const float*)d_in[5];
  const float* qkv_w  = (const float*)d_in[6];
  const float* qkv_b  = (const float*)d_in[7];
  const float* proj_w = (const float*)d_in[8];
  const float* proj_b = (const float*)d_in[9];
  const float* ln2_g  = (const float*)d_in[10];
  const float* ln2_b  = (const float*)d_in[11];
  const float* mlp_w1 = (const float*)d_in[12];
  const float* mlp_b1 = (const float*)d_in[13];
  const float* mlp_w2 = (const float*)d_in[14];
  const float* mlp_b2 = (const float*)d_in[15];
  const float* out_w  = (const float*)d_in[16];
  const float* out_b  = (const float*)d_in[17];
  float* outp = (float*)d_out;

  // workspace layout
  char* p = (char*)d_ws;
  float* seq = (float*)p;                 p += (size_t)M_TOT * E_DIM * 4;   // 32 MB fp32 residual
  unsigned short* bigb = (unsigned short*)p; p += (size_t)M_TOT * 1024 * 2; // 64 MB bf16 (qkv / mlp hidden)
  unsigned short* hb = (unsigned short*)p;   p += (size_t)M_TOT * E_DIM * 2;// 16 MB bf16 (LN / attn out)
  unsigned short* wb = (unsigned short*)p;                                  // 6.4 MB bf16 weights
  unsigned short* qkvT = wb;                         // [L][768][256]
  unsigned short* projT = qkvT + 4 * 768 * 256;      // [L][256][256]
  unsigned short* w1T   = projT + 4 * 256 * 256;     // [L][1024][256]
  unsigned short* w2T   = w1T   + 4 * 1024 * 256;    // [L][256][1024]
  unsigned short* outwb = w2T   + 4 * 256 * 1024;    // [256][256] (already [N,K])

  // one-time-per-call weight conversion
  for (int i = 0; i < 4; i++) {
    wconv_t<<<dim3(24, 8),  256, 0, stream>>>(qkv_w  + (size_t)i*256*768,  qkvT + (size_t)i*768*256,  256, 768);
    wconv_t<<<dim3(8, 8),   256, 0, stream>>>(proj_w + (size_t)i*256*256,  projT+ (size_t)i*256*256,  256, 256);
    wconv_t<<<dim3(32, 8),  256, 0, stream>>>(mlp_w1 + (size_t)i*256*1024, w1T  + (size_t)i*1024*256, 256, 1024);
    wconv_t<<<dim3(8, 32),  256, 0, stream>>>(mlp_w2 + (size_t)i*1024*256, w2T  + (size_t)i*256*1024, 1024, 256);
  }
  bconv<<<64, 256, 0, stream>>>(out_w, outwb, 65536);

  embed_kernel<<<32768, 256, 0, stream>>>(x, in_w, in_b, pos, seq);

  for (int i = 0; i < 4; i++) {
    int shifted = i & 1;
    ln_kernel<<<8192, 256, 0, stream>>>(seq, ln1_g + i*256, ln1_b + i*256, hb);
    // QKV: [32768,256] x [768,256]^T -> bigb bf16
    mgemm<0,0,0,1><<<dim3(6, 256), 256, 0, stream>>>(
        hb, qkvT + (size_t)i*768*256, qkv_b + i*768, nullptr, bigb, M_TOT, 768, 256);
    attn_kernel<<<dim3(512, 8), 64, 0, stream>>>(bigb, hb, shifted);
    // proj + residual into fp32 seq
    mgemm<0,1,0,0><<<dim3(2, 256), 256, 0, stream>>>(
        hb, projT + (size_t)i*256*256, proj_b + i*256, seq, seq, M_TOT, 256, 256);
    ln_kernel<<<8192, 256, 0, stream>>>(seq, ln2_g + i*256, ln2_b + i*256, hb);
    // MLP1 + gelu -> bigb bf16
    mgemm<1,0,0,1><<<dim3(8, 256), 256, 0, stream>>>(
        hb, w1T + (size_t)i*1024*256, mlp_b1 + i*1024, nullptr, bigb, M_TOT, 1024, 256);
    // MLP2 + residual into fp32 seq (K=1024)
    mgemm<0,1,0,0><<<dim3(2, 256), 256, 0, stream>>>(
        bigb, w2T + (size_t)i*256*1024, mlp_b2 + i*256, seq, seq, M_TOT, 256, 1024);
  }

  // final: convert seq -> bf16, then GEMM with out_w (already [N,K]), channel-major fp32 store
  bconv<<<8192, 256, 0, stream>>>(seq, hb, M_TOT * E_DIM);
  mgemm<0,0,1,0><<<dim3(2, 256), 256, 0, stream>>>(
      hb, outwb, out_b, nullptr, outp, M_TOT, 256, 256);
}

// Round 5
// 869.195 us; speedup vs baseline: 5.2654x; 1.3984x over previous
//
#include <hip/hip_runtime.h>
#include <math.h>

// Swin block forward: B=2, IMG=128, E=256, NH=8, HD=32, WS=8, T=64, L=4, HID=1024
#define E_DIM 256
#define NPB 16384           // tokens per batch = 128*128
#define M_TOT 32768         // total tokens

typedef __attribute__((ext_vector_type(4))) float f32x4;
typedef __attribute__((ext_vector_type(8))) short s16x8;

__device__ inline unsigned short f2bu(float f) {       // fp32 -> bf16 bits (RNE)
  union { float f; unsigned int i; } x; x.f = f;
  unsigned int r = x.i + 0x7fffu + ((x.i >> 16) & 1u);
  return (unsigned short)(r >> 16);
}
__device__ inline float bu2f(unsigned short u) {
  union { unsigned int i; float f; } x; x.i = ((unsigned int)u) << 16; return x.f;
}
__device__ inline void gload16(const void* g, void* l) {
  __builtin_amdgcn_global_load_lds(
      (const __attribute__((address_space(1))) void*)g,
      (__attribute__((address_space(3))) void*)l, 16, 0, 0);
}

// ---------------- input embed (fp32 out)
__global__ __launch_bounds__(256) void embed_kernel(
    const float* __restrict__ x, const float* __restrict__ in_w,
    const float* __restrict__ in_b, const float* __restrict__ pos,
    float* __restrict__ seq)
{
  int idx = blockIdx.x * 256 + threadIdx.x;
  int e = idx & 255;
  int n = (idx >> 8) & (NPB - 1);
  int b = idx >> 22;
  float x0 = x[b*3*NPB + 0*NPB + n];
  float x1 = x[b*3*NPB + 1*NPB + n];
  float x2 = x[b*3*NPB + 2*NPB + n];
  float v = x0*in_w[e*3+0] + x1*in_w[e*3+1] + x2*in_w[e*3+2]
          + in_b[e] + pos[(size_t)e*NPB + n];
  seq[((size_t)(b*NPB + n))*E_DIM + e] = v;
}

// ---------------- layernorm fp32 in -> bf16 out, one wave per token
__global__ __launch_bounds__(256) void ln_kernel(
    const float* __restrict__ x, const float* __restrict__ g,
    const float* __restrict__ b, unsigned short* __restrict__ y)
{
  int token = blockIdx.x * 4 + (threadIdx.x >> 6);
  int lane  = threadIdx.x & 63;
  const float4* xr = (const float4*)(x + (size_t)token * E_DIM);
  float4 v = xr[lane];
  float s = v.x + v.y + v.z + v.w;
  #pragma unroll
  for (int off = 32; off; off >>= 1) s += __shfl_xor(s, off);
  float mean = s * (1.0f / E_DIM);
  float d0 = v.x - mean, d1 = v.y - mean, d2 = v.z - mean, d3 = v.w - mean;
  float q = d0*d0 + d1*d1 + d2*d2 + d3*d3;
  #pragma unroll
  for (int off = 32; off; off >>= 1) q += __shfl_xor(q, off);
  float rstd = rsqrtf(q * (1.0f / E_DIM) + 1e-5f);
  float4 gg = ((const float4*)g)[lane];
  float4 bb = ((const float4*)b)[lane];
  ushort4 o;
  o.x = f2bu(d0 * rstd * gg.x + bb.x);
  o.y = f2bu(d1 * rstd * gg.y + bb.y);
  o.z = f2bu(d2 * rstd * gg.z + bb.z);
  o.w = f2bu(d3 * rstd * gg.w + bb.w);
  *(ushort4*)(y + (size_t)token * E_DIM + lane * 4) = o;
}

// ---------------- weight transpose+convert: W[K,N] fp32 -> Wt[N,K] bf16
__global__ __launch_bounds__(256) void wconv_t(
    const float* __restrict__ W, unsigned short* __restrict__ Wt, int K, int N)
{
  __shared__ float t[32][33];
  int nb = blockIdx.x * 32, kb = blockIdx.y * 32;
  int tx = threadIdx.x & 31, ty = threadIdx.x >> 5;   // ty 0..7
  #pragma unroll
  for (int i = 0; i < 32; i += 8)
    t[ty + i][tx] = W[(size_t)(kb + ty + i) * N + nb + tx];
  __syncthreads();
  #pragma unroll
  for (int i = 0; i < 32; i += 8)
    Wt[(size_t)(nb + ty + i) * K + kb + tx] = f2bu(t[tx][ty + i]);
}

// ---------------- elementwise fp32 -> bf16 (n divisible by 1024)
__global__ __launch_bounds__(256) void bconv(
    const float* __restrict__ a, unsigned short* __restrict__ o, int n)
{
  int i = blockIdx.x * 1024 + threadIdx.x * 4;
  float4 v = *(const float4*)(a + i);
  ushort4 u; u.x = f2bu(v.x); u.y = f2bu(v.y); u.z = f2bu(v.z); u.w = f2bu(v.w);
  *(ushort4*)(o + i) = u;
}

// ---------------- bf16 MFMA GEMM, 128x128 tile, BK=32, 4 waves (m97 structure)
template<int ACT, int RES, int OCHW, int OBF>
__global__ __launch_bounds__(256) void mgemm(
    const unsigned short* __restrict__ A, const unsigned short* __restrict__ Wt,
    const float* __restrict__ bias, float* __restrict__ Res,
    void* __restrict__ Cv, int M, int N, int K)
{
  __shared__ unsigned short Al[128 * 32];
  __shared__ unsigned short Bl[128 * 32];
  const int tid  = threadIdx.x;
  const int lane = tid & 63;
  const int wid  = tid >> 6;
  const int wr = wid >> 1, wc = wid & 1;      // 2x2 waves, 64x64 each
  const int bn = blockIdx.x * 128, bm = blockIdx.y * 128;

  f32x4 acc[4][4];
  #pragma unroll
  for (int m = 0; m < 4; m++)
    #pragma unroll
    for (int n = 0; n < 4; n++)
      acc[m][n] = (f32x4){0.f, 0.f, 0.f, 0.f};

  const int srow = tid >> 2;
  const int scol = (tid & 3) * 8;
  const size_t arow = (size_t)(bm + srow);
  const size_t brow = (size_t)(bn + srow);
  char* aldst = (char*)Al + tid * 16;
  char* bldst = (char*)Bl + tid * 16;

  const char* abase = (const char*)Al + (wr*64 + (lane & 15)) * 64 + (lane >> 4) * 16;
  const char* bbase = (const char*)Bl + (wc*64 + (lane & 15)) * 64 + (lane >> 4) * 16;

  for (int k0 = 0; k0 < K; k0 += 32) {
    gload16(A  + arow       * K + k0 + scol, aldst);
    gload16(A  + (arow + 64)* K + k0 + scol, aldst + 4096);
    gload16(Wt + brow       * K + k0 + scol, bldst);
    gload16(Wt + (brow + 64)* K + k0 + scol, bldst + 4096);
    __syncthreads();
    s16x8 af[4], bf_[4];
    #pragma unroll
    for (int m = 0; m < 4; m++) af[m]  = *(const s16x8*)(abase + m * 1024);
    #pragma unroll
    for (int n = 0; n < 4; n++) bf_[n] = *(const s16x8*)(bbase + n * 1024);
    #pragma unroll
    for (int m = 0; m < 4; m++)
      #pragma unroll
      for (int n = 0; n < 4; n++)
        acc[m][n] = __builtin_amdgcn_mfma_f32_16x16x32_bf16(af[m], bf_[n], acc[m][n], 0, 0, 0);
    __syncthreads();
  }

  float bv[4];
  #pragma unroll
  for (int n = 0; n < 4; n++) bv[n] = bias[bn + wc*64 + n*16 + (lane & 15)];

  #pragma unroll
  for (int m = 0; m < 4; m++) {
    int row0 = bm + wr*64 + m*16 + (lane >> 4) * 4;
    #pragma unroll
    for (int n = 0; n < 4; n++) {
      int col = bn + wc*64 + n*16 + (lane & 15);
      if (OCHW) {
        int bb = row0 >> 14, n0 = row0 & (NPB - 1);
        float4 st;
        st.x = acc[m][n][0] + bv[n]; st.y = acc[m][n][1] + bv[n];
        st.z = acc[m][n][2] + bv[n]; st.w = acc[m][n][3] + bv[n];
        *(float4*)((float*)Cv + (size_t)bb * E_DIM * NPB + (size_t)col * NPB + n0) = st;
      } else {
        #pragma unroll
        for (int j = 0; j < 4; j++) {
          int row = row0 + j;
          float v = acc[m][n][j] + bv[n];
          if (ACT) v = 0.5f * v * (1.0f + erff(v * 0.70710678118654752f));
          if (RES) { v += Res[(size_t)row * N + col]; Res[(size_t)row * N + col] = v; }
          else if (OBF) ((unsigned short*)Cv)[(size_t)row * N + col] = f2bu(v);
          else ((float*)Cv)[(size_t)row * N + col] = v;
        }
      }
    }
  }
}

// ---------------- MFMA window attention: one wave per (window, head)
// Swapped QK^T (S^T = mfma(K,Q)) -> lane-local softmax (+2 shfl) -> P,V via
// XOR-swizzled LDS -> PV MFMA. No __syncthreads (waves independent).
template<int SHIFT>
__global__ __launch_bounds__(256) void mattn(
    const unsigned short* __restrict__ qkv, unsigned short* __restrict__ out)
{
  __shared__ unsigned short Vt_s[4][32 * 64];   // [d][t] swizzled, per wave
  __shared__ unsigned short Pl_s[4][64 * 64];   // [q][t] swizzled, per wave
  const int tid = threadIdx.x, wid = tid >> 6, l = tid & 63;
  const int task = blockIdx.x * 4 + wid;        // 0..4095
  const int head = task & 7;
  const int wf = task >> 3;                     // b*256 + win
  const int b = wf >> 8, win = wf & 255;
  const int wh = win >> 4, ww = win & 15;
  unsigned short* Vt = Vt_s[wid];
  unsigned short* Pl = Pl_s[wid];
  const int lg = l >> 4, lc = l & 15;

  // window-token t -> global token id (applies shift roll)
  auto tok_of = [&](int t) -> int {
    int hs = wh * 8 + (t >> 3), ws = ww * 8 + (t & 7);
    if (SHIFT) { hs = (hs + 4) & 127; ws = (ws + 4) & 127; }
    return b * NPB + hs * 128 + ws;
  };
  // Swin mask region id (pre-shift coords), splits at 120/124
  auto reg_of = [&](int t) -> int {
    int hs = wh * 8 + (t >> 3), ws = ww * 8 + (t & 7);
    int a = (hs < 120) ? 0 : ((hs < 124) ? 1 : 2);
    int c = (ws < 120) ? 0 : ((ws < 124) ? 1 : 2);
    return a * 3 + c;
  };

  // Q,K fragments direct from global: lane holds row=(16m+lc), k=lg*8..+7
  s16x8 qf[4], kf[4];
  #pragma unroll
  for (int m = 0; m < 4; m++) {
    const unsigned short* rp = qkv + (size_t)tok_of(m * 16 + lc) * 768 + head * 32 + lg * 8;
    qf[m] = *(const s16x8*)(rp);
    kf[m] = *(const s16x8*)(rp + 256);
  }
  // V staged transposed: Vt[d][t], swizzle u16idx ^= (d&7)<<3
  {
    const unsigned short* vp = qkv + (size_t)tok_of(l) * 768 + 512 + head * 32;
    #pragma unroll
    for (int d8 = 0; d8 < 4; d8++) {
      s16x8 vv = *(const s16x8*)(vp + d8 * 8);
      #pragma unroll
      for (int j = 0; j < 8; j++) {
        int d = d8 * 8 + j;
        Vt[(d * 64 + l) ^ ((d & 7) << 3)] = (unsigned short)vv[j];
      }
    }
  }

  // S^T[kv][q] = mfma(K, Q): lane holds kv rows 16m+4lg+r, q col 16qt+lc
  f32x4 sT[4][4];
  #pragma unroll
  for (int m = 0; m < 4; m++)
    #pragma unroll
    for (int qt = 0; qt < 4; qt++) {
      f32x4 z = (f32x4){0.f, 0.f, 0.f, 0.f};
      sT[m][qt] = __builtin_amdgcn_mfma_f32_16x16x32_bf16(kf[m], qf[qt], z, 0, 0, 0);
    }

  int qreg[4], kreg2[16];
  if (SHIFT) {
    #pragma unroll
    for (int qt = 0; qt < 4; qt++) qreg[qt] = reg_of(qt * 16 + lc);
    #pragma unroll
    for (int m = 0; m < 4; m++)
      #pragma unroll
      for (int r = 0; r < 4; r++) kreg2[m * 4 + r] = reg_of(m * 16 + lg * 4 + r);
  }

  const float scale = 0.17677669529663687f;
  #pragma unroll
  for (int qt = 0; qt < 4; qt++) {
    float mx = -1e30f;
    #pragma unroll
    for (int m = 0; m < 4; m++)
      #pragma unroll
      for (int r = 0; r < 4; r++) {
        float s = sT[m][qt][r] * scale;
        if (SHIFT && qreg[qt] != kreg2[m * 4 + r]) s -= 100.0f;
        sT[m][qt][r] = s;
        mx = fmaxf(mx, s);
      }
    mx = fmaxf(mx, __shfl_xor(mx, 16));
    mx = fmaxf(mx, __shfl_xor(mx, 32));
    float sum = 0.f;
    #pragma unroll
    for (int m = 0; m < 4; m++)
      #pragma unroll
      for (int r = 0; r < 4; r++) {
        float p = __expf(sT[m][qt][r] - mx);
        sT[m][qt][r] = p;
        sum += p;
      }
    sum += __shfl_xor(sum, 16);
    sum += __shfl_xor(sum, 32);
    float inv = 1.0f / sum;                     // fold 1/l into P here
    int q = qt * 16 + lc;
    #pragma unroll
    for (int m = 0; m < 4; m++) {
      ushort4 pk;
      pk.x = f2bu(sT[m][qt][0] * inv);
      pk.y = f2bu(sT[m][qt][1] * inv);
      pk.z = f2bu(sT[m][qt][2] * inv);
      pk.w = f2bu(sT[m][qt][3] * inv);
      *(ushort4*)(Pl + ((q * 64 + m * 16 + lg * 4) ^ ((q & 7) << 3))) = pk;
    }
  }

  // O[q][d] = P·V: A-frag rows q from Pl, B-frag rows d from Vt (both 16B reads)
  f32x4 oacc[4][2];
  #pragma unroll
  for (int qt = 0; qt < 4; qt++)
    #pragma unroll
    for (int n = 0; n < 2; n++)
      oacc[qt][n] = (f32x4){0.f, 0.f, 0.f, 0.f};
  #pragma unroll
  for (int kb = 0; kb < 2; kb++) {
    s16x8 pa[4], vb[2];
    #pragma unroll
    for (int qt = 0; qt < 4; qt++) {
      int q = qt * 16 + lc;
      pa[qt] = *(const s16x8*)(Pl + ((q * 64 + kb * 32 + lg * 8) ^ ((q & 7) << 3)));
    }
    #pragma unroll
    for (int n = 0; n < 2; n++) {
      int d = n * 16 + lc;
      vb[n] = *(const s16x8*)(Vt + ((d * 64 + kb * 32 + lg * 8) ^ ((d & 7) << 3)));
    }
    #pragma unroll
    for (int qt = 0; qt < 4; qt++)
      #pragma unroll
      for (int n = 0; n < 2; n++)
        oacc[qt][n] = __builtin_amdgcn_mfma_f32_16x16x32_bf16(pa[qt], vb[n], oacc[qt][n], 0, 0, 0);
  }

  // write out: lane rows q=16qt+4lg+r, cols d=16n+lc (quarter-wave writes 32B contig)
  #pragma unroll
  for (int qt = 0; qt < 4; qt++)
    #pragma unroll
    for (int r = 0; r < 4; r++) {
      int q = qt * 16 + lg * 4 + r;
      unsigned short* ob = out + (size_t)tok_of(q) * 256 + head * 32;
      ob[lc]      = f2bu(oacc[qt][0][r]);
      ob[16 + lc] = f2bu(oacc[qt][1][r]);
    }
}

extern "C" void kernel_launch(void* const* d_in, const int* in_sizes, int n_in,
                              void* d_out, int out_size, void* d_ws, size_t ws_size,
                              hipStream_t stream) {
  (void)in_sizes; (void)n_in; (void)out_size; (void)ws_size;
  const float* x      = (const float*)d_in[0];
  const float* in_w   = (const float*)d_in[1];
  const float* in_b   = (const float*)d_in[2];
  const float* pos    = (const float*)d_in[3];
  const float* ln1_g  = (const float*)d_in[4];
  const float* ln1_b  = (const float*)d_in[5];
  const float* qkv_w  = (const float*)d_in[6];
  const float* qkv_b  = (const float*)d_in[7];
  const float* proj_w = (const float*)d_in[8];
  const float* proj_b = (const float*)d_in[9];
  const float* ln2_g  = (const float*)d_in[10];
  const float* ln2_b  = (const float*)d_in[11];
  const float* mlp_w1 = (const float*)d_in[12];
  const float* mlp_b1 = (const float*)d_in[13];
  const float* mlp_w2 = (const float*)d_in[14];
  const float* mlp_b2 = (const float*)d_in[15];
  const float* out_w  = (const float*)d_in[16];
  const float* out_b  = (const float*)d_in[17];
  float* outp = (float*)d_out;

  // workspace layout
  char* p = (char*)d_ws;
  float* seq = (float*)p;                 p += (size_t)M_TOT * E_DIM * 4;   // 32 MB fp32 residual
  unsigned short* bigb = (unsigned short*)p; p += (size_t)M_TOT * 1024 * 2; // 64 MB bf16 (qkv / mlp hidden)
  unsigned short* hb = (unsigned short*)p;   p += (size_t)M_TOT * E_DIM * 2;// 16 MB bf16 (LN / attn out)
  unsigned short* wb = (unsigned short*)p;                                  // 6.4 MB bf16 weights
  unsigned short* qkvT = wb;                         // [L][768][256]
  unsigned short* projT = qkvT + 4 * 768 * 256;      // [L][256][256]
  unsigned short* w1T   = projT + 4 * 256 * 256;     // [L][1024][256]
  unsigned short* w2T   = w1T   + 4 * 1024 * 256;    // [L][256][1024]
  unsigned short* outwb = w2T   + 4 * 256 * 1024;    // [256][256] (already [N,K])

  for (int i = 0; i < 4; i++) {
    wconv_t<<<dim3(24, 8),  256, 0, stream>>>(qkv_w  + (size_t)i*256*768,  qkvT + (size_t)i*768*256,  256, 768);
    wconv_t<<<dim3(8, 8),   256, 0, stream>>>(proj_w + (size_t)i*256*256,  projT+ (size_t)i*256*256,  256, 256);
    wconv_t<<<dim3(32, 8),  256, 0, stream>>>(mlp_w1 + (size_t)i*256*1024, w1T  + (size_t)i*1024*256, 256, 1024);
    wconv_t<<<dim3(8, 32),  256, 0, stream>>>(mlp_w2 + (size_t)i*1024*256, w2T  + (size_t)i*256*1024, 1024, 256);
  }
  bconv<<<64, 256, 0, stream>>>(out_w, outwb, 65536);

  embed_kernel<<<32768, 256, 0, stream>>>(x, in_w, in_b, pos, seq);

  for (int i = 0; i < 4; i++) {
    int shifted = i & 1;
    ln_kernel<<<8192, 256, 0, stream>>>(seq, ln1_g + i*256, ln1_b + i*256, hb);
    mgemm<0,0,0,1><<<dim3(6, 256), 256, 0, stream>>>(
        hb, qkvT + (size_t)i*768*256, qkv_b + i*768, nullptr, bigb, M_TOT, 768, 256);
    if (shifted) mattn<1><<<1024, 256, 0, stream>>>(bigb, hb);
    else         mattn<0><<<1024, 256, 0, stream>>>(bigb, hb);
    mgemm<0,1,0,0><<<dim3(2, 256), 256, 0, stream>>>(
        hb, projT + (size_t)i*256*256, proj_b + i*256, seq, seq, M_TOT, 256, 256);
    ln_kernel<<<8192, 256, 0, stream>>>(seq, ln2_g + i*256, ln2_b + i*256, hb);
    mgemm<1,0,0,1><<<dim3(8, 256), 256, 0, stream>>>(
        hb, w1T + (size_t)i*1024*256, mlp_b1 + i*1024, nullptr, bigb, M_TOT, 1024, 256);
    mgemm<0,1,0,0><<<dim3(2, 256), 256, 0, stream>>>(
        bigb, w2T + (size_t)i*256*1024, mlp_b2 + i*256, seq, seq, M_TOT, 256, 1024);
  }

  bconv<<<8192, 256, 0, stream>>>(seq, hb, M_TOT * E_DIM);
  mgemm<0,0,1,0><<<dim3(2, 256), 256, 0, stream>>>(
      hb, outwb, out_b, nullptr, outp, M_TOT, 256, 256);
}

// Round 6
// 828.977 us; speedup vs baseline: 5.5208x; 1.0485x over previous
//
#include <hip/hip_runtime.h>
#include <math.h>

// Swin block forward: B=2, IMG=128, E=256, NH=8, HD=32, WS=8, T=64, L=4, HID=1024
#define E_DIM 256
#define NPB 16384           // tokens per batch = 128*128
#define M_TOT 32768         // total tokens

typedef __attribute__((ext_vector_type(4))) float f32x4;
typedef __attribute__((ext_vector_type(8))) short s16x8;

__device__ inline unsigned short f2bu(float f) {       // fp32 -> bf16 bits (RNE)
  union { float f; unsigned int i; } x; x.f = f;
  unsigned int r = x.i + 0x7fffu + ((x.i >> 16) & 1u);
  return (unsigned short)(r >> 16);
}
__device__ inline float bu2f(unsigned short u) {
  union { unsigned int i; float f; } x; x.i = ((unsigned int)u) << 16; return x.f;
}
__device__ inline void gload16(const void* g, void* l) {
  __builtin_amdgcn_global_load_lds(
      (const __attribute__((address_space(1))) void*)g,
      (__attribute__((address_space(3))) void*)l, 16, 0, 0);
}

// ---------------- input embed: LDS-tiled transpose of pos (coalesced both sides)
__global__ __launch_bounds__(256) void embed_kernel(
    const float* __restrict__ x, const float* __restrict__ in_w,
    const float* __restrict__ in_b, const float* __restrict__ pos,
    float* __restrict__ seq)
{
  __shared__ float ld[32][33];
  int e0 = blockIdx.x * 32;            // 0..224
  int n0 = blockIdx.y * 32;            // 0..32736 (row in M_TOT)
  int b  = n0 >> 14;
  int np = n0 & (NPB - 1);
  int tx = threadIdx.x & 31, ty = threadIdx.x >> 5;   // ty 0..7
  #pragma unroll
  for (int i = 0; i < 4; i++)
    ld[ty + 8*i][tx] = pos[(size_t)(e0 + ty + 8*i) * NPB + np + tx];
  __syncthreads();
  #pragma unroll
  for (int i = 0; i < 4; i++) {
    int n = np + ty + 8*i;
    float x0 = x[(b*3 + 0)*NPB + n];
    float x1 = x[(b*3 + 1)*NPB + n];
    float x2 = x[(b*3 + 2)*NPB + n];
    int e = e0 + tx;
    float v = x0*in_w[e*3+0] + x1*in_w[e*3+1] + x2*in_w[e*3+2] + in_b[e]
            + ld[tx][ty + 8*i];
    seq[(size_t)(n0 + ty + 8*i) * E_DIM + e] = v;
  }
}

// ---------------- layernorm fp32 in -> bf16 out, one wave per token
__global__ __launch_bounds__(256) void ln_kernel(
    const float* __restrict__ x, const float* __restrict__ g,
    const float* __restrict__ b, unsigned short* __restrict__ y)
{
  int token = blockIdx.x * 4 + (threadIdx.x >> 6);
  int lane  = threadIdx.x & 63;
  const float4* xr = (const float4*)(x + (size_t)token * E_DIM);
  float4 v = xr[lane];
  float s = v.x + v.y + v.z + v.w;
  #pragma unroll
  for (int off = 32; off; off >>= 1) s += __shfl_xor(s, off);
  float mean = s * (1.0f / E_DIM);
  float d0 = v.x - mean, d1 = v.y - mean, d2 = v.z - mean, d3 = v.w - mean;
  float q = d0*d0 + d1*d1 + d2*d2 + d3*d3;
  #pragma unroll
  for (int off = 32; off; off >>= 1) q += __shfl_xor(q, off);
  float rstd = rsqrtf(q * (1.0f / E_DIM) + 1e-5f);
  float4 gg = ((const float4*)g)[lane];
  float4 bb = ((const float4*)b)[lane];
  ushort4 o;
  o.x = f2bu(d0 * rstd * gg.x + bb.x);
  o.y = f2bu(d1 * rstd * gg.y + bb.y);
  o.z = f2bu(d2 * rstd * gg.z + bb.z);
  o.w = f2bu(d3 * rstd * gg.w + bb.w);
  *(ushort4*)(y + (size_t)token * E_DIM + lane * 4) = o;
}

// ---------------- weight transpose+convert: W[K,N] fp32 -> Wt[N,K] bf16
__global__ __launch_bounds__(256) void wconv_t(
    const float* __restrict__ W, unsigned short* __restrict__ Wt, int K, int N)
{
  __shared__ float t[32][33];
  int nb = blockIdx.x * 32, kb = blockIdx.y * 32;
  int tx = threadIdx.x & 31, ty = threadIdx.x >> 5;   // ty 0..7
  #pragma unroll
  for (int i = 0; i < 32; i += 8)
    t[ty + i][tx] = W[(size_t)(kb + ty + i) * N + nb + tx];
  __syncthreads();
  #pragma unroll
  for (int i = 0; i < 32; i += 8)
    Wt[(size_t)(nb + ty + i) * K + kb + tx] = f2bu(t[tx][ty + i]);
}

// ---------------- elementwise fp32 -> bf16 (n divisible by 1024)
__global__ __launch_bounds__(256) void bconv(
    const float* __restrict__ a, unsigned short* __restrict__ o, int n)
{
  int i = blockIdx.x * 1024 + threadIdx.x * 4;
  float4 v = *(const float4*)(a + i);
  ushort4 u; u.x = f2bu(v.x); u.y = f2bu(v.y); u.z = f2bu(v.z); u.w = f2bu(v.w);
  *(ushort4*)(o + i) = u;
}

// ---------------- bf16 MFMA GEMM, 128x128 tile, BK=32, 4 waves
// 2-phase double-buffered: STAGE(next) issued before compute(cur), ONE barrier
// per K-step (implicit vmcnt(0) before s_barrier fences the async stage).
template<int ACT, int RES, int OCHW, int OBF>
__global__ __launch_bounds__(256) void mgemm(
    const unsigned short* __restrict__ A, const unsigned short* __restrict__ Wt,
    const float* __restrict__ bias, float* __restrict__ Res,
    void* __restrict__ Cv, int M, int N, int K)
{
  __shared__ unsigned short Al[2][128 * 32];
  __shared__ unsigned short Bl[2][128 * 32];
  const int tid  = threadIdx.x;
  const int lane = tid & 63;
  const int wid  = tid >> 6;
  const int wr = wid >> 1, wc = wid & 1;      // 2x2 waves, 64x64 each
  const int bn = blockIdx.x * 128, bm = blockIdx.y * 128;

  f32x4 acc[4][4];
  #pragma unroll
  for (int m = 0; m < 4; m++)
    #pragma unroll
    for (int n = 0; n < 4; n++)
      acc[m][n] = (f32x4){0.f, 0.f, 0.f, 0.f};

  const int srow = tid >> 2;            // 0..63
  const int scol = (tid & 3) * 8;       // bf16 element offset (16B chunk)
  const unsigned short* aSrc = A  + (size_t)(bm + srow) * K + scol;
  const unsigned short* bSrc = Wt + (size_t)(bn + srow) * K + scol;

  const int aoff = (wr*64 + (lane & 15)) * 64 + (lane >> 4) * 16;  // bytes
  const int boff = (wc*64 + (lane & 15)) * 64 + (lane >> 4) * 16;

  // prologue: stage tile 0
  {
    char* ad = (char*)Al[0] + tid * 16;
    char* bd = (char*)Bl[0] + tid * 16;
    gload16(aSrc,          ad);
    gload16(aSrc + 64*K,   ad + 4096);
    gload16(bSrc,          bd);
    gload16(bSrc + 64*K,   bd + 4096);
  }
  __syncthreads();

  const int nt = K >> 5;
  int cur = 0;
  for (int t = 0; t < nt; ++t) {
    if (t + 1 < nt) {                   // prefetch next K-tile into other buffer
      int k0 = (t + 1) << 5;
      char* ad = (char*)Al[cur ^ 1] + tid * 16;
      char* bd = (char*)Bl[cur ^ 1] + tid * 16;
      gload16(aSrc + k0,        ad);
      gload16(aSrc + 64*K + k0, ad + 4096);
      gload16(bSrc + k0,        bd);
      gload16(bSrc + 64*K + k0, bd + 4096);
    }
    const char* ab = (const char*)Al[cur] + aoff;
    const char* bb = (const char*)Bl[cur] + boff;
    s16x8 af[4], bf_[4];
    #pragma unroll
    for (int m = 0; m < 4; m++) af[m]  = *(const s16x8*)(ab + m * 1024);
    #pragma unroll
    for (int n = 0; n < 4; n++) bf_[n] = *(const s16x8*)(bb + n * 1024);
    #pragma unroll
    for (int m = 0; m < 4; m++)
      #pragma unroll
      for (int n = 0; n < 4; n++)
        acc[m][n] = __builtin_amdgcn_mfma_f32_16x16x32_bf16(af[m], bf_[n], acc[m][n], 0, 0, 0);
    __syncthreads();                    // drains stage (vmcnt) + read-done fence
    cur ^= 1;
  }

  // epilogue: C/D map col = lane&15, row = (lane>>4)*4 + j
  float bv[4];
  #pragma unroll
  for (int n = 0; n < 4; n++) bv[n] = bias[bn + wc*64 + n*16 + (lane & 15)];

  #pragma unroll
  for (int m = 0; m < 4; m++) {
    int row0 = bm + wr*64 + m*16 + (lane >> 4) * 4;
    #pragma unroll
    for (int n = 0; n < 4; n++) {
      int col = bn + wc*64 + n*16 + (lane & 15);
      if (OCHW) {
        int bb2 = row0 >> 14, n0 = row0 & (NPB - 1);
        float4 st;
        st.x = acc[m][n][0] + bv[n]; st.y = acc[m][n][1] + bv[n];
        st.z = acc[m][n][2] + bv[n]; st.w = acc[m][n][3] + bv[n];
        *(float4*)((float*)Cv + (size_t)bb2 * E_DIM * NPB + (size_t)col * NPB + n0) = st;
      } else {
        #pragma unroll
        for (int j = 0; j < 4; j++) {
          int row = row0 + j;
          float v = acc[m][n][j] + bv[n];
          if (ACT) v = 0.5f * v * (1.0f + erff(v * 0.70710678118654752f));
          if (RES) { v += Res[(size_t)row * N + col]; Res[(size_t)row * N + col] = v; }
          else if (OBF) ((unsigned short*)Cv)[(size_t)row * N + col] = f2bu(v);
          else ((float*)Cv)[(size_t)row * N + col] = v;
        }
      }
    }
  }
}

// ---------------- MFMA window attention: one wave per (window, head)
template<int SHIFT>
__global__ __launch_bounds__(256) void mattn(
    const unsigned short* __restrict__ qkv, unsigned short* __restrict__ out)
{
  __shared__ unsigned short Vt_s[4][32 * 64];   // [d][t] swizzled, per wave
  __shared__ unsigned short Pl_s[4][64 * 64];   // [q][t] swizzled, per wave
  const int tid = threadIdx.x, wid = tid >> 6, l = tid & 63;
  const int task = blockIdx.x * 4 + wid;        // 0..4095
  const int head = task & 7;
  const int wf = task >> 3;                     // b*256 + win
  const int b = wf >> 8, win = wf & 255;
  const int wh = win >> 4, ww = win & 15;
  unsigned short* Vt = Vt_s[wid];
  unsigned short* Pl = Pl_s[wid];
  const int lg = l >> 4, lc = l & 15;

  auto tok_of = [&](int t) -> int {
    int hs = wh * 8 + (t >> 3), ws = ww * 8 + (t & 7);
    if (SHIFT) { hs = (hs + 4) & 127; ws = (ws + 4) & 127; }
    return b * NPB + hs * 128 + ws;
  };
  auto reg_of = [&](int t) -> int {
    int hs = wh * 8 + (t >> 3), ws = ww * 8 + (t & 7);
    int a = (hs < 120) ? 0 : ((hs < 124) ? 1 : 2);
    int c = (ws < 120) ? 0 : ((ws < 124) ? 1 : 2);
    return a * 3 + c;
  };

  s16x8 qf[4], kf[4];
  #pragma unroll
  for (int m = 0; m < 4; m++) {
    const unsigned short* rp = qkv + (size_t)tok_of(m * 16 + lc) * 768 + head * 32 + lg * 8;
    qf[m] = *(const s16x8*)(rp);
    kf[m] = *(const s16x8*)(rp + 256);
  }
  {
    const unsigned short* vp = qkv + (size_t)tok_of(l) * 768 + 512 + head * 32;
    #pragma unroll
    for (int d8 = 0; d8 < 4; d8++) {
      s16x8 vv = *(const s16x8*)(vp + d8 * 8);
      #pragma unroll
      for (int j = 0; j < 8; j++) {
        int d = d8 * 8 + j;
        Vt[(d * 64 + l) ^ ((d & 7) << 3)] = (unsigned short)vv[j];
      }
    }
  }

  f32x4 sT[4][4];
  #pragma unroll
  for (int m = 0; m < 4; m++)
    #pragma unroll
    for (int qt = 0; qt < 4; qt++) {
      f32x4 z = (f32x4){0.f, 0.f, 0.f, 0.f};
      sT[m][qt] = __builtin_amdgcn_mfma_f32_16x16x32_bf16(kf[m], qf[qt], z, 0, 0, 0);
    }

  int qreg[4], kreg2[16];
  if (SHIFT) {
    #pragma unroll
    for (int qt = 0; qt < 4; qt++) qreg[qt] = reg_of(qt * 16 + lc);
    #pragma unroll
    for (int m = 0; m < 4; m++)
      #pragma unroll
      for (int r = 0; r < 4; r++) kreg2[m * 4 + r] = reg_of(m * 16 + lg * 4 + r);
  }

  const float scale = 0.17677669529663687f;
  #pragma unroll
  for (int qt = 0; qt < 4; qt++) {
    float mx = -1e30f;
    #pragma unroll
    for (int m = 0; m < 4; m++)
      #pragma unroll
      for (int r = 0; r < 4; r++) {
        float s = sT[m][qt][r] * scale;
        if (SHIFT && qreg[qt] != kreg2[m * 4 + r]) s -= 100.0f;
        sT[m][qt][r] = s;
        mx = fmaxf(mx, s);
      }
    mx = fmaxf(mx, __shfl_xor(mx, 16));
    mx = fmaxf(mx, __shfl_xor(mx, 32));
    float sum = 0.f;
    #pragma unroll
    for (int m = 0; m < 4; m++)
      #pragma unroll
      for (int r = 0; r < 4; r++) {
        float p = __expf(sT[m][qt][r] - mx);
        sT[m][qt][r] = p;
        sum += p;
      }
    sum += __shfl_xor(sum, 16);
    sum += __shfl_xor(sum, 32);
    float inv = 1.0f / sum;                     // fold 1/l into P here
    int q = qt * 16 + lc;
    #pragma unroll
    for (int m = 0; m < 4; m++) {
      ushort4 pk;
      pk.x = f2bu(sT[m][qt][0] * inv);
      pk.y = f2bu(sT[m][qt][1] * inv);
      pk.z = f2bu(sT[m][qt][2] * inv);
      pk.w = f2bu(sT[m][qt][3] * inv);
      *(ushort4*)(Pl + ((q * 64 + m * 16 + lg * 4) ^ ((q & 7) << 3))) = pk;
    }
  }

  f32x4 oacc[4][2];
  #pragma unroll
  for (int qt = 0; qt < 4; qt++)
    #pragma unroll
    for (int n = 0; n < 2; n++)
      oacc[qt][n] = (f32x4){0.f, 0.f, 0.f, 0.f};
  #pragma unroll
  for (int kb = 0; kb < 2; kb++) {
    s16x8 pa[4], vb[2];
    #pragma unroll
    for (int qt = 0; qt < 4; qt++) {
      int q = qt * 16 + lc;
      pa[qt] = *(const s16x8*)(Pl + ((q * 64 + kb * 32 + lg * 8) ^ ((q & 7) << 3)));
    }
    #pragma unroll
    for (int n = 0; n < 2; n++) {
      int d = n * 16 + lc;
      vb[n] = *(const s16x8*)(Vt + ((d * 64 + kb * 32 + lg * 8) ^ ((d & 7) << 3)));
    }
    #pragma unroll
    for (int qt = 0; qt < 4; qt++)
      #pragma unroll
      for (int n = 0; n < 2; n++)
        oacc[qt][n] = __builtin_amdgcn_mfma_f32_16x16x32_bf16(pa[qt], vb[n], oacc[qt][n], 0, 0, 0);
  }

  #pragma unroll
  for (int qt = 0; qt < 4; qt++)
    #pragma unroll
    for (int r = 0; r < 4; r++) {
      int q = qt * 16 + lg * 4 + r;
      unsigned short* ob = out + (size_t)tok_of(q) * 256 + head * 32;
      ob[lc]      = f2bu(oacc[qt][0][r]);
      ob[16 + lc] = f2bu(oacc[qt][1][r]);
    }
}

extern "C" void kernel_launch(void* const* d_in, const int* in_sizes, int n_in,
                              void* d_out, int out_size, void* d_ws, size_t ws_size,
                              hipStream_t stream) {
  (void)in_sizes; (void)n_in; (void)out_size; (void)ws_size;
  const float* x      = (const float*)d_in[0];
  const float* in_w   = (const float*)d_in[1];
  const float* in_b   = (const float*)d_in[2];
  const float* pos    = (const float*)d_in[3];
  const float* ln1_g  = (const float*)d_in[4];
  const float* ln1_b  = (const float*)d_in[5];
  const float* qkv_w  = (const float*)d_in[6];
  const float* qkv_b  = (const float*)d_in[7];
  const float* proj_w = (const float*)d_in[8];
  const float* proj_b = (const float*)d_in[9];
  const float* ln2_g  = (const float*)d_in[10];
  const float* ln2_b  = (const float*)d_in[11];
  const float* mlp_w1 = (const float*)d_in[12];
  const float* mlp_b1 = (const float*)d_in[13];
  const float* mlp_w2 = (const float*)d_in[14];
  const float* mlp_b2 = (const float*)d_in[15];
  const float* out_w  = (const float*)d_in[16];
  const float* out_b  = (const float*)d_in[17];
  float* outp = (float*)d_out;

  // workspace layout
  char* p = (char*)d_ws;
  float* seq = (float*)p;                 p += (size_t)M_TOT * E_DIM * 4;   // 32 MB fp32 residual
  unsigned short* bigb = (unsigned short*)p; p += (size_t)M_TOT * 1024 * 2; // 64 MB bf16 (qkv / mlp hidden)
  unsigned short* hb = (unsigned short*)p;   p += (size_t)M_TOT * E_DIM * 2;// 16 MB bf16 (LN / attn out)
  unsigned short* wb = (unsigned short*)p;                                  // 6.4 MB bf16 weights
  unsigned short* qkvT = wb;                         // [L][768][256]
  unsigned short* projT = qkvT + 4 * 768 * 256;      // [L][256][256]
  unsigned short* w1T   = projT + 4 * 256 * 256;     // [L][1024][256]
  unsigned short* w2T   = w1T   + 4 * 1024 * 256;    // [L][256][1024]
  unsigned short* outwb = w2T   + 4 * 256 * 1024;    // [256][256] (already [N,K])

  for (int i = 0; i < 4; i++) {
    wconv_t<<<dim3(24, 8),  256, 0, stream>>>(qkv_w  + (size_t)i*256*768,  qkvT + (size_t)i*768*256,  256, 768);
    wconv_t<<<dim3(8, 8),   256, 0, stream>>>(proj_w + (size_t)i*256*256,  projT+ (size_t)i*256*256,  256, 256);
    wconv_t<<<dim3(32, 8),  256, 0, stream>>>(mlp_w1 + (size_t)i*256*1024, w1T  + (size_t)i*1024*256, 256, 1024);
    wconv_t<<<dim3(8, 32),  256, 0, stream>>>(mlp_w2 + (size_t)i*1024*256, w2T  + (size_t)i*256*1024, 1024, 256);
  }
  bconv<<<64, 256, 0, stream>>>(out_w, outwb, 65536);

  embed_kernel<<<dim3(8, 1024), 256, 0, stream>>>(x, in_w, in_b, pos, seq);

  for (int i = 0; i < 4; i++) {
    int shifted = i & 1;
    ln_kernel<<<8192, 256, 0, stream>>>(seq, ln1_g + i*256, ln1_b + i*256, hb);
    mgemm<0,0,0,1><<<dim3(6, 256), 256, 0, stream>>>(
        hb, qkvT + (size_t)i*768*256, qkv_b + i*768, nullptr, bigb, M_TOT, 768, 256);
    if (shifted) mattn<1><<<1024, 256, 0, stream>>>(bigb, hb);
    else         mattn<0><<<1024, 256, 0, stream>>>(bigb, hb);
    mgemm<0,1,0,0><<<dim3(2, 256), 256, 0, stream>>>(
        hb, projT + (size_t)i*256*256, proj_b + i*256, seq, seq, M_TOT, 256, 256);
    ln_kernel<<<8192, 256, 0, stream>>>(seq, ln2_g + i*256, ln2_b + i*256, hb);
    mgemm<1,0,0,1><<<dim3(8, 256), 256, 0, stream>>>(
        hb, w1T + (size_t)i*1024*256, mlp_b1 + i*1024, nullptr, bigb, M_TOT, 1024, 256);
    mgemm<0,1,0,0><<<dim3(2, 256), 256, 0, stream>>>(
        bigb, w2T + (size_t)i*256*1024, mlp_b2 + i*256, seq, seq, M_TOT, 256, 1024);
  }

  bconv<<<8192, 256, 0, stream>>>(seq, hb, M_TOT * E_DIM);
  mgemm<0,0,1,0><<<dim3(2, 256), 256, 0, stream>>>(
      hb, outwb, out_b, nullptr, outp, M_TOT, 256, 256);
}